// Round 9
// baseline (1534.534 us; speedup 1.0000x reference)
//
#include <hip/hip_runtime.h>

#define N_NODES 100000
#define N_EDGES 1600000

typedef _Float16 f16;
typedef _Float16 f16x8 __attribute__((ext_vector_type(8)));
typedef float f32x4 __attribute__((ext_vector_type(4)));

__device__ __forceinline__ float sigf(float x) { return 1.f / (1.f + __expf(-x)); }

// ---------------- graph preprocessing ----------------

__global__ void count_kernel(const int* __restrict__ src, const int* __restrict__ dst,
                             int* __restrict__ cntO, int* __restrict__ cntI,
                             int* __restrict__ slotO, int* __restrict__ slotI)
{
    int i = blockIdx.x * 256 + threadIdx.x;
    if (i >= N_EDGES) return;
    slotO[i] = atomicAdd(&cntO[dst[i]], 1);   // pout CSR grouped by dst
    slotI[i] = atomicAdd(&cntI[src[i]], 1);   // pin CSR grouped by src
}

__global__ __launch_bounds__(1024) void scan2_kernel(const int* __restrict__ cntA, int* __restrict__ rpA,
                                                     const int* __restrict__ cntB, int* __restrict__ rpB,
                                                     int n)
{
    const int* cnt = blockIdx.x ? cntB : cntA;
    int* rp = blockIdx.x ? rpB : rpA;
    __shared__ int wsum[16];
    __shared__ int carry;
    int tid = threadIdx.x, lane = tid & 63, wid = tid >> 6;
    if (tid == 0) { rp[0] = 0; carry = 0; }
    __syncthreads();
    for (int base = 0; base < n; base += 1024) {
        int idx = base + tid;
        int x = (idx < n) ? cnt[idx] : 0;
        #pragma unroll
        for (int off = 1; off < 64; off <<= 1) {
            int y = __shfl_up(x, off);
            if (lane >= off) x += y;
        }
        if (lane == 63) wsum[wid] = x;
        __syncthreads();
        if (wid == 0 && lane < 16) {
            int y = wsum[lane];
            #pragma unroll
            for (int off = 1; off < 16; off <<= 1) {
                int z = __shfl_up(y, off);
                if (lane >= off) y += z;
            }
            wsum[lane] = y;
        }
        __syncthreads();
        int tot = x + (wid ? wsum[wid - 1] : 0) + carry;
        if (idx < n) rp[idx + 1] = tot;
        __syncthreads();
        if (tid == 1023) carry = tot;
        __syncthreads();
    }
}

// Scatter packed {neighbor, ew_bits} — no atomics (slots precomputed).
__global__ void fill_kernel(const int* __restrict__ src, const int* __restrict__ dst,
                            const float* __restrict__ ew,
                            const int* __restrict__ rpO, const int* __restrict__ rpI,
                            const int* __restrict__ slotO, const int* __restrict__ slotI,
                            int2* __restrict__ adj2O, int2* __restrict__ adj2I)
{
    int i = blockIdx.x * 256 + threadIdx.x;
    if (i >= N_EDGES) return;
    int s = src[i], d = dst[i];
    int wb = __float_as_int(ew[i]);
    int2 eo; eo.x = s; eo.y = wb;
    adj2O[rpO[d] + slotO[i]] = eo;
    int2 ei; ei.x = d; ei.y = wb;
    adj2I[rpI[s] + slotI[i]] = ei;
}

// Per-node degree sums -> inverse degrees (no adjacency rewrites).
__global__ void finalize_kernel(const int* __restrict__ rpO, const int2* __restrict__ adj2O,
                                float* __restrict__ di_inv,
                                const int* __restrict__ rpI, const int2* __restrict__ adj2I,
                                float* __restrict__ do_inv)
{
    int n = blockIdx.x * 256 + threadIdx.x;
    if (n >= N_NODES) return;
    float s = 0.f;
    for (int e = rpO[n]; e < rpO[n + 1]; ++e) s += __int_as_float(adj2O[e].y);
    di_inv[n] = (s > 0.f) ? 1.f / s : 0.f;
    float t = 0.f;
    for (int e = rpI[n]; e < rpI[n + 1]; ++e) t += __int_as_float(adj2I[e].y);
    do_inv[n] = (t > 0.f) ? 1.f / t : 0.f;
}

// ---------------- weight preprocessing (Chebyshev-folded, one merged launch) --------
// Parts: p0=u (W00+W10-W02-W12), p1=t1o (W01), p2=s2o (2*W02), p3=t1i (W11), p4=s2i (2*W12).
__device__ __forceinline__ void prep_w_dev(const float* __restrict__ W, int C, int SA, int PWA,
                                           int rA, int gLo, int gHi, int COLS, int XS,
                                           int idx, f16* __restrict__ outw)
{
    int total = (SA + XS) * COLS * 32;
    if (idx >= total) return;
    int k32 = idx & 31;
    int c = (idx >> 5) % COLS;
    int s = (idx >> 5) / COLS;
    int g = (c < 64 || gHi < 0) ? gLo : gHi;
    int col = (c >= 64) ? c - 64 : c;
    int p, r;
    if (s < SA) { p = s / PWA; r = rA + (s % PWA) * 32 + k32; }
    else {
        if (k32 < 10) { p = k32 >> 1; r = k32 & 1; }
        else { outw[idx] = (f16)0.f; return; }
    }
    auto wv = [&](int d, int k) {
        return W[((((size_t)(g * 2 + d) * 3 + k) * C + r) << 6) + col];
    };
    float val;
    if (p == 0)      val = wv(0, 0) + wv(1, 0) - wv(0, 2) - wv(1, 2);
    else if (p == 1) val = wv(0, 1);
    else if (p == 2) val = 2.f * wv(0, 2);
    else if (p == 3) val = wv(1, 1);
    else             val = 2.f * wv(1, 2);
    outw[idx] = (f16)val;
}

__device__ __forceinline__ void prep_enc1_dev(const float* __restrict__ W, int idx,
                                              float* __restrict__ outw)
{
    if (idx >= 1280) return;
    int c = idx & 127, k = idx >> 7;
    int g = (c < 64) ? 0 : 2, col = c & 63;
    int p = k >> 1, r = k & 1;
    const int C = 66;
    auto wv = [&](int d, int kk) {
        return W[((((size_t)(g * 2 + d) * 3 + kk) * C + r) << 6) + col];
    };
    float val;
    if (p == 0)      val = wv(0, 0) + wv(1, 0) - wv(0, 2) - wv(1, 2);
    else if (p == 1) val = wv(0, 1);
    else if (p == 2) val = 2.f * wv(0, 2);
    else if (p == 3) val = wv(1, 1);
    else             val = 2.f * wv(1, 2);
    outw[idx] = val;
}

// One launch for all 7 weight preps; blockIdx.x range-dispatch.
__global__ void prep_all(const float* __restrict__ e1W, const float* __restrict__ e2W,
                         const float* __restrict__ d1W, const float* __restrict__ d2W,
                         f16* __restrict__ wE2, f16* __restrict__ wD1zr, f16* __restrict__ wD1c,
                         f16* __restrict__ wD2zr, f16* __restrict__ wD2cA, f16* __restrict__ wD2cB,
                         float* __restrict__ We1)
{
    int b = blockIdx.x, tid = threadIdx.x;
    if (b < 160)      prep_w_dev(e2W, 128, 10, 2, 0,  0,  2, 128, 0, b * 256 + tid, wE2);
    else if (b < 336) prep_w_dev(d1W, 66,  10, 2, 2,  0,  1, 128, 1, (b - 160) * 256 + tid, wD1zr);
    else if (b < 424) prep_w_dev(d1W, 66,  10, 2, 2,  2, -1,  64, 1, (b - 336) * 256 + tid, wD1c);
    else if (b < 744) prep_w_dev(d2W, 128, 20, 4, 0,  0,  1, 128, 0, (b - 424) * 256 + tid, wD2zr);
    else if (b < 824) prep_w_dev(d2W, 128, 10, 2, 0,  2, -1,  64, 0, (b - 744) * 256 + tid, wD2cA);
    else if (b < 904) prep_w_dev(d2W, 128, 10, 2, 64, 2, -1,  64, 0, (b - 824) * 256 + tid, wD2cB);
    else              prep_enc1_dev(e1W, (b - 904) * 256 + tid, We1);
}

// xcat fp16 [N][32]: cols 0-1 = xs, 2-9 = (t1o, s2o, t1i, s2i), 10-31 zero
__global__ void xcat_init(const float* __restrict__ x, f16* __restrict__ xcat)
{
    int i = blockIdx.x * 256 + threadIdx.x;
    if (i >= N_NODES * 32) return;
    int n = i >> 5, c = i & 31;
    float v = (c < 2) ? x[(size_t)n * 24 + c] : 0.f;  // x[:, :, 0, :] of (4,25000,12,2)
    xcat[i] = (f16)v;
}

// 2-channel pure propagation inside xcat, dual-direction via blockIdx.y
__global__ void prop2d_kernel(const int* __restrict__ rpA, const int2* __restrict__ adjA,
                              const float* __restrict__ scA, int cinA, int coutA,
                              const int* __restrict__ rpB, const int2* __restrict__ adjB,
                              const float* __restrict__ scB, int cinB, int coutB,
                              f16* __restrict__ xcat)
{
    const int* rp; const int2* adj; const float* sc; int cin, cout;
    if (blockIdx.y == 0) { rp = rpA; adj = adjA; sc = scA; cin = cinA; cout = coutA; }
    else                 { rp = rpB; adj = adjB; sc = scB; cin = cinB; cout = coutB; }
    int n = blockIdx.x * 256 + threadIdx.x;
    if (n >= N_NODES) return;
    int beg = rp[n], end = rp[n + 1];
    float a0 = 0.f, a1 = 0.f;
    for (int e = beg; e < end; ++e) {
        int2 v = adj[e];
        float w = sc[v.x];
        a0 += w * (float)xcat[((size_t)v.x << 5) + cin];
        a1 += w * (float)xcat[((size_t)v.x << 5) + cin + 1];
    }
    xcat[((size_t)n << 5) + cout] = (f16)a0;
    xcat[((size_t)n << 5) + cout + 1] = (f16)a1;
}

// ---------------- propagation: LPN lanes/node, f16x8 loads, scale from L2 ----------
template <int LPN>
__global__ __launch_bounds__(256) void propk(
    const int* __restrict__ rpA, const int2* __restrict__ adjA, const float* __restrict__ scA,
    const f16* __restrict__ uA, f16* __restrict__ oA,
    const int* __restrict__ rpB, const int2* __restrict__ adjB, const float* __restrict__ scB,
    const f16* __restrict__ uB, f16* __restrict__ oB,
    int ldu, int ldo)
{
    const int* RP; const int2* ADJ; const float* SC; const f16* U; f16* OUT;
    if (blockIdx.y == 0) { RP = rpA; ADJ = adjA; SC = scA; U = uA; OUT = oA; }
    else                 { RP = rpB; ADJ = adjB; SC = scB; U = uB; OUT = oB; }
    constexpr int NPB = 256 / LPN;
    int node = blockIdx.x * NPB + (threadIdx.x / LPN);
    int l = threadIdx.x % LPN;
    if (node >= N_NODES) return;
    int b = RP[node], e = RP[node + 1];
    float a[8] = {0.f, 0.f, 0.f, 0.f, 0.f, 0.f, 0.f, 0.f};
    float c[8] = {0.f, 0.f, 0.f, 0.f, 0.f, 0.f, 0.f, 0.f};
    int i = b;
    for (; i + 1 < e; i += 2) {
        int2 n0 = ADJ[i], n1 = ADJ[i + 1];
        float w0 = SC[n0.x], w1 = SC[n1.x];
        f16x8 u0 = *(const f16x8*)(U + (size_t)n0.x * ldu + (l << 3));
        f16x8 u1 = *(const f16x8*)(U + (size_t)n1.x * ldu + (l << 3));
        #pragma unroll
        for (int j = 0; j < 8; ++j) { a[j] += w0 * (float)u0[j]; c[j] += w1 * (float)u1[j]; }
    }
    if (i < e) {
        int2 n0 = ADJ[i];
        float w = SC[n0.x];
        f16x8 u0 = *(const f16x8*)(U + (size_t)n0.x * ldu + (l << 3));
        #pragma unroll
        for (int j = 0; j < 8; ++j) a[j] += w * (float)u0[j];
    }
    f16x8 r;
    #pragma unroll
    for (int j = 0; j < 8; ++j) r[j] = (f16)(a[j] + c[j]);
    *(f16x8*)(OUT + (size_t)node * ldo + (l << 3)) = r;
}

// ---------------- MFMA GEMM over virtually-concatenated parts ----------------
// out = ACT( sum_steps A_s[N,32] @ Wstep_s[32,COLS] + addX + bias )
// Single-step staging (K=32/barrier pair, 15.3 KB LDS -> 10 blocks/CU).
// ACT: 0 none, 2 tanh,
//      4 fused GRU-h0 (COLS=128: z=sig(lo), t=tanh(hi), out[.,os]+(col-64) = (1-z)*t),
//      5 fused z|R*h  (COLS=128: out[.,os]=sig(lo)=z, out2[.,o2s]=sig(hi)*hmul[.,hs]),
//      6 fused GRU combine+relu (COLS=64: out[.,os] = relu(zin*hmul + (1-zin)*tanh(v)))
template <int SA, int XS, int COLS, int ACT>
__global__ __launch_bounds__(256) void mfma_gemm(
    const f16* __restrict__ uA, const f16* __restrict__ tA0, const f16* __restrict__ tA1,
    const f16* __restrict__ tA2, const f16* __restrict__ tA3,
    int lAu, int cAu, int lAt, int cAt,
    const f16* __restrict__ xcat, const f16* __restrict__ wstep,
    const f16* __restrict__ addX, int axs,
    const float* __restrict__ biasLo, const float* __restrict__ biasHi,
    f16* __restrict__ out, int os,
    const f16* __restrict__ hmul, int hs,
    f16* __restrict__ out2, int o2s, const f16* __restrict__ zin)
{
    __shared__ f16 As[64][40];     // [row][k], pad 40 halves
    __shared__ f16 Ws[COLS][40];   // [col][k]
    const int row0 = blockIdx.x * 64;
    const int tid = threadIdx.x;
    const int wave = tid >> 6, lane = tid & 63;
    const int lr = lane & 15, lk = lane >> 4;
    const int ka = lk << 3;
    constexpr int RT = (COLS == 128) ? 4 : 2;
    constexpr int PWA = SA / 5;
    constexpr int STEPS = SA + XS;
    f32x4 acc[RT][2] = {};
    const f16* tA[4] = { tA0, tA1, tA2, tA3 };

    #pragma unroll
    for (int s = 0; s < STEPS; ++s) {
        __syncthreads();
        {   // stage A tile: 64 rows x 32 halves
            int r = tid >> 2, seg = tid & 3;
            int grow = row0 + r;
            const f16* srcp;
            if (s < SA) {
                int pp = s / PWA, ch = s % PWA;
                const f16* base = (pp == 0) ? uA : tA[pp - 1];
                int ld = (pp == 0) ? lAu : lAt;
                int co = (pp == 0) ? cAu : cAt;
                srcp = base + (size_t)grow * ld + co + ch * 32 + (seg << 3);
            } else {
                srcp = xcat + (((size_t)grow) << 5) + (seg << 3);
            }
            int4 v = (grow < N_NODES) ? *(const int4*)srcp : make_int4(0, 0, 0, 0);
            *(int4*)&As[r][seg << 3] = v;
        }
        for (int q = tid; q < COLS * 4; q += 256) {
            int cc = q >> 2, sg = q & 3;
            *(int4*)&Ws[cc][sg << 3] =
                *(const int4*)(wstep + (((size_t)(s * COLS + cc)) << 5) + (sg << 3));
        }
        __syncthreads();
        if (COLS == 128) {
            f16x8 b0 = *(const f16x8*)&Ws[wave * 32 + lr][ka];
            f16x8 b1 = *(const f16x8*)&Ws[wave * 32 + 16 + lr][ka];
            #pragma unroll
            for (int rt = 0; rt < RT; ++rt) {
                f16x8 a = *(const f16x8*)&As[rt * 16 + lr][ka];
                acc[rt][0] = __builtin_amdgcn_mfma_f32_16x16x32_f16(a, b0, acc[rt][0], 0, 0, 0);
                acc[rt][1] = __builtin_amdgcn_mfma_f32_16x16x32_f16(a, b1, acc[rt][1], 0, 0, 0);
            }
        } else {
            f16x8 b0 = *(const f16x8*)&Ws[(wave & 1) * 32 + lr][ka];
            f16x8 b1 = *(const f16x8*)&Ws[(wave & 1) * 32 + 16 + lr][ka];
            #pragma unroll
            for (int rt = 0; rt < RT; ++rt) {
                f16x8 a = *(const f16x8*)&As[(wave >> 1) * 32 + rt * 16 + lr][ka];
                acc[rt][0] = __builtin_amdgcn_mfma_f32_16x16x32_f16(a, b0, acc[rt][0], 0, 0, 0);
                acc[rt][1] = __builtin_amdgcn_mfma_f32_16x16x32_f16(a, b1, acc[rt][1], 0, 0, 0);
            }
        }
    }
    // D layout: col=lane&15 (+16*ct+32*wavepart), row=(lane>>4)*4+reg
    if constexpr (ACT == 4) {
        __shared__ float zbuf[64][65];
        float treg[RT][2][4];
        #pragma unroll
        for (int rt = 0; rt < RT; ++rt)
            #pragma unroll
            for (int ct = 0; ct < 2; ++ct) {
                int col = wave * 32 + ct * 16 + lr;
                #pragma unroll
                for (int j = 0; j < 4; ++j) {
                    int r = rt * 16 + lk * 4 + j;
                    float v = acc[rt][ct][j] + ((col < 64) ? biasLo[col] : biasHi[col - 64]);
                    if (col < 64) zbuf[r][col] = sigf(v);
                    else          treg[rt][ct][j] = tanhf(v);
                }
            }
        __syncthreads();
        #pragma unroll
        for (int rt = 0; rt < RT; ++rt)
            #pragma unroll
            for (int ct = 0; ct < 2; ++ct) {
                int col = wave * 32 + ct * 16 + lr;
                if (col < 64) continue;
                #pragma unroll
                for (int j = 0; j < 4; ++j) {
                    int r = rt * 16 + lk * 4 + j;
                    int grow = row0 + r;
                    if (grow >= N_NODES) continue;
                    float h = (1.f - zbuf[r][col - 64]) * treg[rt][ct][j];
                    out[(size_t)grow * os + (col - 64)] = (f16)h;
                }
            }
    } else if constexpr (ACT == 5) {
        #pragma unroll
        for (int rt = 0; rt < RT; ++rt)
            #pragma unroll
            for (int ct = 0; ct < 2; ++ct) {
                int col = wave * 32 + ct * 16 + lr;
                #pragma unroll
                for (int j = 0; j < 4; ++j) {
                    int grow = row0 + rt * 16 + lk * 4 + j;
                    if (grow >= N_NODES) continue;
                    float v = acc[rt][ct][j] + ((col < 64) ? biasLo[col] : biasHi[col - 64]);
                    float sg = sigf(v);
                    if (col < 64)
                        out[(size_t)grow * os + col] = (f16)sg;     // z gate
                    else
                        out2[(size_t)grow * o2s + (col - 64)] =     // g = R*h
                            (f16)(sg * (float)hmul[(size_t)grow * hs + (col - 64)]);
                }
            }
    } else {
        #pragma unroll
        for (int rt = 0; rt < RT; ++rt) {
            int rbase = (COLS == 128) ? rt * 16 : (wave >> 1) * 32 + rt * 16;
            #pragma unroll
            for (int ct = 0; ct < 2; ++ct) {
                int col = ((COLS == 128) ? wave * 32 : (wave & 1) * 32) + ct * 16 + lr;
                #pragma unroll
                for (int j = 0; j < 4; ++j) {
                    int grow = row0 + rbase + lk * 4 + j;
                    if (grow >= N_NODES) continue;
                    float v = acc[rt][ct][j];
                    if (addX)   v += (float)addX[(size_t)grow * axs + col];
                    if (biasLo) v += (col < 64) ? biasLo[col] : biasHi[col - 64];
                    if (ACT == 2) v = tanhf(v);
                    else if (ACT == 6) {
                        float t = tanhf(v);
                        float z = (float)zin[((size_t)grow << 6) + col];
                        float hv = (float)hmul[(size_t)grow * hs + col];
                        v = fmaxf(z * hv + (1.f - z) * t, 0.f);
                    }
                    out[(size_t)grow * os + col] = (f16)v;
                }
            }
        }
    }
}

// ---------------- fused enc1 (K=10 VALU GEMM + GRU combine) -> c1 = relu(h)||h ------
__global__ __launch_bounds__(256) void enc1_kernel(const f16* __restrict__ xcat,
                                                   const float* __restrict__ We1,
                                                   const float* __restrict__ b,
                                                   f16* __restrict__ c1)
{
    int node = (blockIdx.x << 2) + (threadIdx.x >> 6);
    int lane = threadIdx.x & 63;
    float az = b[lane], at = b[128 + lane];
    #pragma unroll
    for (int k = 0; k < 10; ++k) {
        float xv = (float)xcat[((size_t)node << 5) + k];
        az += xv * We1[k * 128 + lane];
        at += xv * We1[k * 128 + 64 + lane];
    }
    float z = sigf(az), t = tanhf(at);
    float h = (1.f - z) * t;
    size_t o = (size_t)node * 128 + lane;
    c1[o] = (f16)fmaxf(h, 0.f);   // h1r half
    c1[o + 64] = (f16)h;          // h1 half
}

// ---------------- final: GRU combine + linear [64->2] ----------------
__global__ __launch_bounds__(256) void final_kernel(const f16* __restrict__ zb,
                                                    const f16* __restrict__ gT,  // stride 128
                                                    const f16* __restrict__ h2,  // stride 128
                                                    const float* __restrict__ lW, const float* __restrict__ lb,
                                                    float* __restrict__ out)
{
    int node = (blockIdx.x << 2) + (threadIdx.x >> 6);
    int lane = threadIdx.x & 63;
    float z = (float)zb[((size_t)node << 6) + lane];
    float d = z * (float)h2[(size_t)node * 128 + lane]
            + (1.f - z) * (float)gT[(size_t)node * 128 + lane];
    float s0 = d * lW[lane * 2];
    float s1 = d * lW[lane * 2 + 1];
    #pragma unroll
    for (int off = 32; off > 0; off >>= 1) {
        s0 += __shfl_down(s0, off);
        s1 += __shfl_down(s1, off);
    }
    if (lane == 0) {
        out[node * 2]     = s0 + lb[0];
        out[node * 2 + 1] = s1 + lb[1];
    }
}

// ---------------- driver ----------------

extern "C" void kernel_launch(void* const* d_in, const int* in_sizes, int n_in,
                              void* d_out, int out_size, void* d_ws, size_t ws_size,
                              hipStream_t stream)
{
    (void)in_sizes; (void)n_in; (void)out_size;
    const float* x   = (const float*)d_in[0];
    const int*  eidx = (const int*)d_in[1];
    const float* ew  = (const float*)d_in[2];
    const float* e1W = (const float*)d_in[3];
    const float* e1b = (const float*)d_in[4];
    const float* e2W = (const float*)d_in[5];
    const float* e2b = (const float*)d_in[6];
    const float* d1W = (const float*)d_in[7];
    const float* d1b = (const float*)d_in[8];
    const float* d2W = (const float*)d_in[9];
    const float* d2b = (const float*)d_in[10];
    const float* lW  = (const float*)d_in[11];
    const float* lb  = (const float*)d_in[12];
    const int* src = eidx;
    const int* dst = eidx + N_EDGES;
    const int N = N_NODES, E = N_EDGES;

    char* p = (char*)d_ws;
    auto carve = [&](size_t bytes) { char* r = p; p += (bytes + 255) & ~(size_t)255; return r; };
    size_t NC = (size_t)N * 128 * 2;             // [N,128] f16 = 25.6 MB
    int*   cntO  = (int*)carve((size_t)2 * N * 4);
    int*   cntI  = cntO + N;
    int*   rpO   = (int*)carve((size_t)(N + 1) * 4);
    int*   rpI   = (int*)carve((size_t)(N + 1) * 4);
    int*   slotO = (int*)carve((size_t)2 * E * 4);  // slotO|slotI; dead after fill -> zb
    int*   slotI = slotO + E;
    int2*  adj2O = (int2*)carve((size_t)E * 8);     // {nbr, ew} — live all launch
    int2*  adj2I = (int2*)carve((size_t)E * 8);
    f16*   ct0   = (f16*)carve(NC);                 // t1o | (hi: gT in dec2)
    f16*   ct1   = (f16*)carve(NC);                 // s2o | (hi: g)
    f16*   ct2   = (f16*)carve(NC);                 // t1i
    f16*   ct3   = (f16*)carve(NC);                 // s2i
    float* do_inv = (float*)carve((size_t)N * 4);
    float* di_inv = (float*)carve((size_t)N * 4);
    f16*   xcat = (f16*)carve((size_t)N * 32 * 2);
    f16*   c1   = (f16*)carve(NC);   // h1r || h1
    f16*   c2   = (f16*)carve(NC);   // hA || h2
    f16* wE2   = (f16*)carve((size_t)10 * 128 * 32 * 2);
    f16* wD1zr = (f16*)carve((size_t)11 * 128 * 32 * 2);
    f16* wD1c  = (f16*)carve((size_t)11 * 64 * 32 * 2);
    f16* wD2zr = (f16*)carve((size_t)20 * 128 * 32 * 2);
    f16* wD2cA = (f16*)carve((size_t)10 * 64 * 32 * 2);
    f16* wD2cB = (f16*)carve((size_t)10 * 64 * 32 * 2);
    float* We1 = (float*)carve((size_t)1280 * 4);

    f16* zb = (f16*)slotO;           // [N,64] — slot region dead after fill
    f16* g1 = ct1 + 64;              // [N,64] stride 128 (cols 64-127 of ct1)
    f16* gT = ct0 + 64;              // [N,64] stride 128 (cols 64-127 of ct0)

    size_t needed = (size_t)(p - (char*)d_ws);
    if (needed > ws_size) return;   // clean failure (diagnosable) instead of fault

    const int eg = (E + 255) / 256;
    const int ng = (N + 255) / 256;
    const int GB = 25000;           // N/4 node-wave grid

    // --- graph prep ---
    hipMemsetAsync(cntO, 0, (size_t)2 * N * 4, stream);
    count_kernel<<<eg, 256, 0, stream>>>(src, dst, cntO, cntI, slotO, slotI);
    scan2_kernel<<<2, 1024, 0, stream>>>(cntO, rpO, cntI, rpI, N);
    fill_kernel<<<eg, 256, 0, stream>>>(src, dst, ew, rpO, rpI, slotO, slotI, adj2O, adj2I);
    finalize_kernel<<<ng, 256, 0, stream>>>(rpO, adj2O, di_inv, rpI, adj2I, do_inv);

    // --- weight prep (single merged launch) ---
    prep_all<<<909, 256, 0, stream>>>(e1W, e2W, d1W, d2W,
                                      wE2, wD1zr, wD1c, wD2zr, wD2cA, wD2cB, We1);

    // --- x features + 2-channel Chebyshev basis (pure P hops, both dirs batched) ---
    xcat_init<<<(N * 32 + 255) / 256, 256, 0, stream>>>(x, xcat);
    dim3 ng2(ng, 2);
    prop2d_kernel<<<ng2, 256, 0, stream>>>(rpO, adj2O, do_inv, 0, 2,
                                           rpI, adj2I, di_inv, 0, 6, xcat);
    prop2d_kernel<<<ng2, 256, 0, stream>>>(rpO, adj2O, do_inv, 2, 4,
                                           rpI, adj2I, di_inv, 6, 8, xcat);

    auto props128 = [&](const f16* u) {   // ct0..ct3 = (t1o, s2o, t1i, s2i), full 128 cols
        dim3 pg(N / 16, 2);
        propk<16><<<pg, 256, 0, stream>>>(rpO, adj2O, do_inv, u, ct0,
                                          rpI, adj2I, di_inv, u, ct2, 128, 128);
        propk<16><<<pg, 256, 0, stream>>>(rpO, adj2O, do_inv, ct0, ct1,
                                          rpI, adj2I, di_inv, ct2, ct3, 128, 128);
    };
    auto props64 = [&](const f16* u, int ldu) {  // ct cols 0-63 only
        dim3 pg(N / 32, 2);
        propk<8><<<pg, 256, 0, stream>>>(rpO, adj2O, do_inv, u, ct0,
                                         rpI, adj2I, di_inv, u, ct2, ldu, 128);
        propk<8><<<pg, 256, 0, stream>>>(rpO, adj2O, do_inv, ct0, ct1,
                                         rpI, adj2I, di_inv, ct2, ct3, 128, 128);
    };
    const int gg = (N + 63) / 64;

    // enc1 -> c1 = relu(h1)||h1
    enc1_kernel<<<GB, 256, 0, stream>>>(xcat, We1, e1b, c1);
    // combined props of (h1r, h1)
    props128(c1);
    // enc2 (u = h1r half): fused GRU-h0 writes h2 into c2 cols 64-127
    mfma_gemm<10, 0, 128, 4><<<gg, 256, 0, stream>>>(
        c1, ct0, ct1, ct2, ct3, 128, 0, 128, 0, nullptr, wE2,
        nullptr, 0, e2b, e2b + 128, c2 + 64, 128, nullptr, 0, nullptr, 0, nullptr);
    // dec1 z|R (u = h1 half): z -> zb, g1 = R*h1 -> ct1 hi (row-private epilogue write)
    mfma_gemm<10, 1, 128, 5><<<gg, 256, 0, stream>>>(
        c1, ct0, ct1, ct2, ct3, 128, 64, 128, 64, xcat, wD1zr,
        nullptr, 0, d1b, d1b + 64, zb, 64, c1 + 64, 128, g1, 128, nullptr);
    // candidate props of g1 into ct cols 0-63 (g1 itself lives in ct1 cols 64-127)
    props64(g1, 128);
    // dec1 candidate: fused combine+relu writes hA into c2 cols 0-63
    mfma_gemm<10, 1, 64, 6><<<gg, 256, 0, stream>>>(
        g1, ct0, ct1, ct2, ct3, 128, 0, 128, 0, xcat, wD1c,
        nullptr, 0, d1b + 128, d1b + 128, c2, 128, c1 + 64, 128, nullptr, 0, zb);
    // combined props of (hA, h2)
    props128(c2);
    // dec2 z|R: single K=640 GEMM; z -> zb, g2 = R*h2 -> ct1 hi
    mfma_gemm<20, 0, 128, 5><<<gg, 256, 0, stream>>>(
        c2, ct0, ct1, ct2, ct3, 128, 0, 128, 0, nullptr, wD2zr,
        nullptr, 0, d2b, d2b + 64, zb, 64, c2 + 64, 128, g1, 128, nullptr);
    // dec2 candidate part A (hA rows) -> gT partial (ct0 hi; disjoint cols from readers)
    mfma_gemm<10, 0, 64, 0><<<gg, 256, 0, stream>>>(
        c2, ct0, ct1, ct2, ct3, 128, 0, 128, 0, nullptr, wD2cA,
        nullptr, 0, nullptr, nullptr, gT, 128, nullptr, 0, nullptr, 0, nullptr);
    // candidate props of g2 into ct cols 0-63
    props64(g1, 128);
    // dec2 candidate part B (g2 rows) + gT + bias + tanh -> gT (in-place add)
    mfma_gemm<10, 0, 64, 2><<<gg, 256, 0, stream>>>(
        g1, ct0, ct1, ct2, ct3, 128, 0, 128, 0, nullptr, wD2cB,
        gT, 128, d2b + 128, d2b + 128, gT, 128, nullptr, 0, nullptr, 0, nullptr);
    final_kernel<<<GB, 256, 0, stream>>>(zb, gT, c2 + 64, lW, lb, (float*)d_out);
}

// Round 10
// 1433.732 us; speedup vs baseline: 1.0703x; 1.0703x over previous
//
#include <hip/hip_runtime.h>

#define N_NODES 100000
#define N_EDGES 1600000

typedef _Float16 f16;
typedef _Float16 f16x8 __attribute__((ext_vector_type(8)));
typedef float f32x4 __attribute__((ext_vector_type(4)));

__device__ __forceinline__ float sigf(float x) { return 1.f / (1.f + __expf(-x)); }

// ---------------- graph preprocessing ----------------

__global__ void count_kernel(const int* __restrict__ src, const int* __restrict__ dst,
                             int* __restrict__ cntO, int* __restrict__ cntI,
                             int* __restrict__ slotO, int* __restrict__ slotI)
{
    int i = blockIdx.x * 256 + threadIdx.x;
    if (i >= N_EDGES) return;
    slotO[i] = atomicAdd(&cntO[dst[i]], 1);   // pout CSR grouped by dst
    slotI[i] = atomicAdd(&cntI[src[i]], 1);   // pin CSR grouped by src
}

__global__ __launch_bounds__(1024) void scan2_kernel(const int* __restrict__ cntA, int* __restrict__ rpA,
                                                     const int* __restrict__ cntB, int* __restrict__ rpB,
                                                     int n)
{
    const int* cnt = blockIdx.x ? cntB : cntA;
    int* rp = blockIdx.x ? rpB : rpA;
    __shared__ int wsum[16];
    __shared__ int carry;
    int tid = threadIdx.x, lane = tid & 63, wid = tid >> 6;
    if (tid == 0) { rp[0] = 0; carry = 0; }
    __syncthreads();
    for (int base = 0; base < n; base += 1024) {
        int idx = base + tid;
        int x = (idx < n) ? cnt[idx] : 0;
        #pragma unroll
        for (int off = 1; off < 64; off <<= 1) {
            int y = __shfl_up(x, off);
            if (lane >= off) x += y;
        }
        if (lane == 63) wsum[wid] = x;
        __syncthreads();
        if (wid == 0 && lane < 16) {
            int y = wsum[lane];
            #pragma unroll
            for (int off = 1; off < 16; off <<= 1) {
                int z = __shfl_up(y, off);
                if (lane >= off) y += z;
            }
            wsum[lane] = y;
        }
        __syncthreads();
        int tot = x + (wid ? wsum[wid - 1] : 0) + carry;
        if (idx < n) rp[idx + 1] = tot;
        __syncthreads();
        if (tid == 1023) carry = tot;
        __syncthreads();
    }
}

// Scatter packed {neighbor, ew_bits} — no atomics (slots precomputed).
__global__ void fill_kernel(const int* __restrict__ src, const int* __restrict__ dst,
                            const float* __restrict__ ew,
                            const int* __restrict__ rpO, const int* __restrict__ rpI,
                            const int* __restrict__ slotO, const int* __restrict__ slotI,
                            int2* __restrict__ adj2O, int2* __restrict__ adj2I)
{
    int i = blockIdx.x * 256 + threadIdx.x;
    if (i >= N_EDGES) return;
    int s = src[i], d = dst[i];
    int wb = __float_as_int(ew[i]);
    int2 eo; eo.x = s; eo.y = wb;
    adj2O[rpO[d] + slotO[i]] = eo;
    int2 ei; ei.x = d; ei.y = wb;
    adj2I[rpI[s] + slotI[i]] = ei;
}

// Compact int2 CSR -> int adjacency (4 B/edge for prop streams) + inverse degrees.
__global__ void finalize_kernel(const int* __restrict__ rpO, const int2* __restrict__ adj2O,
                                int* __restrict__ adjO, float* __restrict__ di_inv,
                                const int* __restrict__ rpI, const int2* __restrict__ adj2I,
                                int* __restrict__ adjI, float* __restrict__ do_inv)
{
    int n = blockIdx.x * 256 + threadIdx.x;
    if (n >= N_NODES) return;
    float s = 0.f;
    for (int e = rpO[n]; e < rpO[n + 1]; ++e) {
        int2 v = adj2O[e];
        adjO[e] = v.x;
        s += __int_as_float(v.y);
    }
    di_inv[n] = (s > 0.f) ? 1.f / s : 0.f;
    float t = 0.f;
    for (int e = rpI[n]; e < rpI[n + 1]; ++e) {
        int2 v = adj2I[e];
        adjI[e] = v.x;
        t += __int_as_float(v.y);
    }
    do_inv[n] = (t > 0.f) ? 1.f / t : 0.f;
}

// ---------------- weight preprocessing (Chebyshev-folded, one merged launch) --------
// Parts: p0=u (W00+W10-W02-W12), p1=t1o (W01), p2=s2o (2*W02), p3=t1i (W11), p4=s2i (2*W12).
__device__ __forceinline__ void prep_w_dev(const float* __restrict__ W, int C, int SA, int PWA,
                                           int rA, int gLo, int gHi, int COLS, int XS,
                                           int idx, f16* __restrict__ outw)
{
    int total = (SA + XS) * COLS * 32;
    if (idx >= total) return;
    int k32 = idx & 31;
    int c = (idx >> 5) % COLS;
    int s = (idx >> 5) / COLS;
    int g = (c < 64 || gHi < 0) ? gLo : gHi;
    int col = (c >= 64) ? c - 64 : c;
    int p, r;
    if (s < SA) { p = s / PWA; r = rA + (s % PWA) * 32 + k32; }
    else {
        if (k32 < 10) { p = k32 >> 1; r = k32 & 1; }
        else { outw[idx] = (f16)0.f; return; }
    }
    auto wv = [&](int d, int k) {
        return W[((((size_t)(g * 2 + d) * 3 + k) * C + r) << 6) + col];
    };
    float val;
    if (p == 0)      val = wv(0, 0) + wv(1, 0) - wv(0, 2) - wv(1, 2);
    else if (p == 1) val = wv(0, 1);
    else if (p == 2) val = 2.f * wv(0, 2);
    else if (p == 3) val = wv(1, 1);
    else             val = 2.f * wv(1, 2);
    outw[idx] = (f16)val;
}

__device__ __forceinline__ void prep_enc1_dev(const float* __restrict__ W, int idx,
                                              float* __restrict__ outw)
{
    if (idx >= 1280) return;
    int c = idx & 127, k = idx >> 7;
    int g = (c < 64) ? 0 : 2, col = c & 63;
    int p = k >> 1, r = k & 1;
    const int C = 66;
    auto wv = [&](int d, int kk) {
        return W[((((size_t)(g * 2 + d) * 3 + kk) * C + r) << 6) + col];
    };
    float val;
    if (p == 0)      val = wv(0, 0) + wv(1, 0) - wv(0, 2) - wv(1, 2);
    else if (p == 1) val = wv(0, 1);
    else if (p == 2) val = 2.f * wv(0, 2);
    else if (p == 3) val = wv(1, 1);
    else             val = 2.f * wv(1, 2);
    outw[idx] = val;
}

// One launch for all 7 weight preps; blockIdx.x range-dispatch.
__global__ void prep_all(const float* __restrict__ e1W, const float* __restrict__ e2W,
                         const float* __restrict__ d1W, const float* __restrict__ d2W,
                         f16* __restrict__ wE2, f16* __restrict__ wD1zr, f16* __restrict__ wD1c,
                         f16* __restrict__ wD2zr, f16* __restrict__ wD2cA, f16* __restrict__ wD2cB,
                         float* __restrict__ We1)
{
    int b = blockIdx.x, tid = threadIdx.x;
    if (b < 160)      prep_w_dev(e2W, 128, 10, 2, 0,  0,  2, 128, 0, b * 256 + tid, wE2);
    else if (b < 336) prep_w_dev(d1W, 66,  10, 2, 2,  0,  1, 128, 1, (b - 160) * 256 + tid, wD1zr);
    else if (b < 424) prep_w_dev(d1W, 66,  10, 2, 2,  2, -1,  64, 1, (b - 336) * 256 + tid, wD1c);
    else if (b < 744) prep_w_dev(d2W, 128, 20, 4, 0,  0,  1, 128, 0, (b - 424) * 256 + tid, wD2zr);
    else if (b < 824) prep_w_dev(d2W, 128, 10, 2, 0,  2, -1,  64, 0, (b - 744) * 256 + tid, wD2cA);
    else if (b < 904) prep_w_dev(d2W, 128, 10, 2, 64, 2, -1,  64, 0, (b - 824) * 256 + tid, wD2cB);
    else              prep_enc1_dev(e1W, (b - 904) * 256 + tid, We1);
}

// xcat fp16 [N][32]: cols 0-1 = xs, 2-9 = (t1o, s2o, t1i, s2i), 10-31 zero
__global__ void xcat_init(const float* __restrict__ x, f16* __restrict__ xcat)
{
    int i = blockIdx.x * 256 + threadIdx.x;
    if (i >= N_NODES * 32) return;
    int n = i >> 5, c = i & 31;
    float v = (c < 2) ? x[(size_t)n * 24 + c] : 0.f;  // x[:, :, 0, :] of (4,25000,12,2)
    xcat[i] = (f16)v;
}

// 2-channel pure propagation inside xcat, dual-direction via blockIdx.y
__global__ void prop2d_kernel(const int* __restrict__ rpA, const int* __restrict__ adjA,
                              const float* __restrict__ scA, int cinA, int coutA,
                              const int* __restrict__ rpB, const int* __restrict__ adjB,
                              const float* __restrict__ scB, int cinB, int coutB,
                              f16* __restrict__ xcat)
{
    const int* rp; const int* adj; const float* sc; int cin, cout;
    if (blockIdx.y == 0) { rp = rpA; adj = adjA; sc = scA; cin = cinA; cout = coutA; }
    else                 { rp = rpB; adj = adjB; sc = scB; cin = cinB; cout = coutB; }
    int n = blockIdx.x * 256 + threadIdx.x;
    if (n >= N_NODES) return;
    int beg = rp[n], end = rp[n + 1];
    float a0 = 0.f, a1 = 0.f;
    for (int e = beg; e < end; ++e) {
        int s = adj[e];
        float w = sc[s];
        a0 += w * (float)xcat[((size_t)s << 5) + cin];
        a1 += w * (float)xcat[((size_t)s << 5) + cin + 1];
    }
    xcat[((size_t)n << 5) + cout] = (f16)a0;
    xcat[((size_t)n << 5) + cout + 1] = (f16)a1;
}

// ---------------- propagation: LPN lanes/node, f16x8 loads, 4B adj + L2 scale ------
template <int LPN>
__global__ __launch_bounds__(256) void propk(
    const int* __restrict__ rpA, const int* __restrict__ adjA, const float* __restrict__ scA,
    const f16* __restrict__ uA, f16* __restrict__ oA,
    const int* __restrict__ rpB, const int* __restrict__ adjB, const float* __restrict__ scB,
    const f16* __restrict__ uB, f16* __restrict__ oB,
    int ldu, int ldo)
{
    const int* RP; const int* ADJ; const float* SC; const f16* U; f16* OUT;
    if (blockIdx.y == 0) { RP = rpA; ADJ = adjA; SC = scA; U = uA; OUT = oA; }
    else                 { RP = rpB; ADJ = adjB; SC = scB; U = uB; OUT = oB; }
    constexpr int NPB = 256 / LPN;
    int node = blockIdx.x * NPB + (threadIdx.x / LPN);
    int l = threadIdx.x % LPN;
    if (node >= N_NODES) return;
    int b = RP[node], e = RP[node + 1];
    float a[8] = {0.f, 0.f, 0.f, 0.f, 0.f, 0.f, 0.f, 0.f};
    float c[8] = {0.f, 0.f, 0.f, 0.f, 0.f, 0.f, 0.f, 0.f};
    int i = b;
    for (; i + 1 < e; i += 2) {
        int s0 = ADJ[i], s1 = ADJ[i + 1];
        float w0 = SC[s0], w1 = SC[s1];
        f16x8 u0 = *(const f16x8*)(U + (size_t)s0 * ldu + (l << 3));
        f16x8 u1 = *(const f16x8*)(U + (size_t)s1 * ldu + (l << 3));
        #pragma unroll
        for (int j = 0; j < 8; ++j) { a[j] += w0 * (float)u0[j]; c[j] += w1 * (float)u1[j]; }
    }
    if (i < e) {
        int s = ADJ[i];
        float w = SC[s];
        f16x8 u0 = *(const f16x8*)(U + (size_t)s * ldu + (l << 3));
        #pragma unroll
        for (int j = 0; j < 8; ++j) a[j] += w * (float)u0[j];
    }
    f16x8 r;
    #pragma unroll
    for (int j = 0; j < 8; ++j) r[j] = (f16)(a[j] + c[j]);
    *(f16x8*)(OUT + (size_t)node * ldo + (l << 3)) = r;
}

// ---------------- MFMA GEMM over virtually-concatenated parts ----------------
// out = ACT( sum_steps A_s[N,32] @ Wstep_s[32,COLS] + addX + bias )
// Single-step staging (K=32/barrier pair, 15.3 KB LDS -> high occupancy).
// ACT: 0 none, 2 tanh,
//      4 fused GRU-h0 (COLS=128: z=sig(lo), t=tanh(hi), out[.,os]+(col-64) = (1-z)*t),
//      5 fused z|R*h  (COLS=128: out[.,os]=sig(lo)=z, out2[.,o2s]=sig(hi)*hmul[.,hs]),
//      6 fused GRU combine+relu (COLS=64: out[.,os] = relu(zin*hmul + (1-zin)*tanh(v)))
template <int SA, int XS, int COLS, int ACT>
__global__ __launch_bounds__(256) void mfma_gemm(
    const f16* __restrict__ uA, const f16* __restrict__ tA0, const f16* __restrict__ tA1,
    const f16* __restrict__ tA2, const f16* __restrict__ tA3,
    int lAu, int cAu, int lAt, int cAt,
    const f16* __restrict__ xcat, const f16* __restrict__ wstep,
    const f16* __restrict__ addX, int axs,
    const float* __restrict__ biasLo, const float* __restrict__ biasHi,
    f16* __restrict__ out, int os,
    const f16* __restrict__ hmul, int hs,
    f16* __restrict__ out2, int o2s, const f16* __restrict__ zin)
{
    __shared__ f16 As[64][40];     // [row][k], pad 40 halves
    __shared__ f16 Ws[COLS][40];   // [col][k]
    const int row0 = blockIdx.x * 64;
    const int tid = threadIdx.x;
    const int wave = tid >> 6, lane = tid & 63;
    const int lr = lane & 15, lk = lane >> 4;
    const int ka = lk << 3;
    constexpr int RT = (COLS == 128) ? 4 : 2;
    constexpr int PWA = SA / 5;
    constexpr int STEPS = SA + XS;
    f32x4 acc[RT][2] = {};
    const f16* tA[4] = { tA0, tA1, tA2, tA3 };

    #pragma unroll
    for (int s = 0; s < STEPS; ++s) {
        __syncthreads();
        {   // stage A tile: 64 rows x 32 halves
            int r = tid >> 2, seg = tid & 3;
            int grow = row0 + r;
            const f16* srcp;
            if (s < SA) {
                int pp = s / PWA, ch = s % PWA;
                const f16* base = (pp == 0) ? uA : tA[pp - 1];
                int ld = (pp == 0) ? lAu : lAt;
                int co = (pp == 0) ? cAu : cAt;
                srcp = base + (size_t)grow * ld + co + ch * 32 + (seg << 3);
            } else {
                srcp = xcat + (((size_t)grow) << 5) + (seg << 3);
            }
            int4 v = (grow < N_NODES) ? *(const int4*)srcp : make_int4(0, 0, 0, 0);
            *(int4*)&As[r][seg << 3] = v;
        }
        for (int q = tid; q < COLS * 4; q += 256) {
            int cc = q >> 2, sg = q & 3;
            *(int4*)&Ws[cc][sg << 3] =
                *(const int4*)(wstep + (((size_t)(s * COLS + cc)) << 5) + (sg << 3));
        }
        __syncthreads();
        if (COLS == 128) {
            f16x8 b0 = *(const f16x8*)&Ws[wave * 32 + lr][ka];
            f16x8 b1 = *(const f16x8*)&Ws[wave * 32 + 16 + lr][ka];
            #pragma unroll
            for (int rt = 0; rt < RT; ++rt) {
                f16x8 a = *(const f16x8*)&As[rt * 16 + lr][ka];
                acc[rt][0] = __builtin_amdgcn_mfma_f32_16x16x32_f16(a, b0, acc[rt][0], 0, 0, 0);
                acc[rt][1] = __builtin_amdgcn_mfma_f32_16x16x32_f16(a, b1, acc[rt][1], 0, 0, 0);
            }
        } else {
            f16x8 b0 = *(const f16x8*)&Ws[(wave & 1) * 32 + lr][ka];
            f16x8 b1 = *(const f16x8*)&Ws[(wave & 1) * 32 + 16 + lr][ka];
            #pragma unroll
            for (int rt = 0; rt < RT; ++rt) {
                f16x8 a = *(const f16x8*)&As[(wave >> 1) * 32 + rt * 16 + lr][ka];
                acc[rt][0] = __builtin_amdgcn_mfma_f32_16x16x32_f16(a, b0, acc[rt][0], 0, 0, 0);
                acc[rt][1] = __builtin_amdgcn_mfma_f32_16x16x32_f16(a, b1, acc[rt][1], 0, 0, 0);
            }
        }
    }
    // D layout: col=lane&15 (+16*ct+32*wavepart), row=(lane>>4)*4+reg
    if constexpr (ACT == 4) {
        __shared__ float zbuf[64][65];
        float treg[RT][2][4];
        #pragma unroll
        for (int rt = 0; rt < RT; ++rt)
            #pragma unroll
            for (int ct = 0; ct < 2; ++ct) {
                int col = wave * 32 + ct * 16 + lr;
                #pragma unroll
                for (int j = 0; j < 4; ++j) {
                    int r = rt * 16 + lk * 4 + j;
                    float v = acc[rt][ct][j] + ((col < 64) ? biasLo[col] : biasHi[col - 64]);
                    if (col < 64) zbuf[r][col] = sigf(v);
                    else          treg[rt][ct][j] = tanhf(v);
                }
            }
        __syncthreads();
        #pragma unroll
        for (int rt = 0; rt < RT; ++rt)
            #pragma unroll
            for (int ct = 0; ct < 2; ++ct) {
                int col = wave * 32 + ct * 16 + lr;
                if (col < 64) continue;
                #pragma unroll
                for (int j = 0; j < 4; ++j) {
                    int r = rt * 16 + lk * 4 + j;
                    int grow = row0 + r;
                    if (grow >= N_NODES) continue;
                    float h = (1.f - zbuf[r][col - 64]) * treg[rt][ct][j];
                    out[(size_t)grow * os + (col - 64)] = (f16)h;
                }
            }
    } else if constexpr (ACT == 5) {
        #pragma unroll
        for (int rt = 0; rt < RT; ++rt)
            #pragma unroll
            for (int ct = 0; ct < 2; ++ct) {
                int col = wave * 32 + ct * 16 + lr;
                #pragma unroll
                for (int j = 0; j < 4; ++j) {
                    int grow = row0 + rt * 16 + lk * 4 + j;
                    if (grow >= N_NODES) continue;
                    float v = acc[rt][ct][j] + ((col < 64) ? biasLo[col] : biasHi[col - 64]);
                    float sg = sigf(v);
                    if (col < 64)
                        out[(size_t)grow * os + col] = (f16)sg;     // z gate
                    else
                        out2[(size_t)grow * o2s + (col - 64)] =     // g = R*h
                            (f16)(sg * (float)hmul[(size_t)grow * hs + (col - 64)]);
                }
            }
    } else {
        #pragma unroll
        for (int rt = 0; rt < RT; ++rt) {
            int rbase = (COLS == 128) ? rt * 16 : (wave >> 1) * 32 + rt * 16;
            #pragma unroll
            for (int ct = 0; ct < 2; ++ct) {
                int col = ((COLS == 128) ? wave * 32 : (wave & 1) * 32) + ct * 16 + lr;
                #pragma unroll
                for (int j = 0; j < 4; ++j) {
                    int grow = row0 + rbase + lk * 4 + j;
                    if (grow >= N_NODES) continue;
                    float v = acc[rt][ct][j];
                    if (addX)   v += (float)addX[(size_t)grow * axs + col];
                    if (biasLo) v += (col < 64) ? biasLo[col] : biasHi[col - 64];
                    if (ACT == 2) v = tanhf(v);
                    else if (ACT == 6) {
                        float t = tanhf(v);
                        float z = (float)zin[((size_t)grow << 6) + col];
                        float hv = (float)hmul[(size_t)grow * hs + col];
                        v = fmaxf(z * hv + (1.f - z) * t, 0.f);
                    }
                    out[(size_t)grow * os + col] = (f16)v;
                }
            }
        }
    }
}

// ---------------- fused enc1 (K=10 VALU GEMM + GRU combine) -> c1 = relu(h)||h ------
__global__ __launch_bounds__(256) void enc1_kernel(const f16* __restrict__ xcat,
                                                   const float* __restrict__ We1,
                                                   const float* __restrict__ b,
                                                   f16* __restrict__ c1)
{
    int node = (blockIdx.x << 2) + (threadIdx.x >> 6);
    int lane = threadIdx.x & 63;
    float az = b[lane], at = b[128 + lane];
    #pragma unroll
    for (int k = 0; k < 10; ++k) {
        float xv = (float)xcat[((size_t)node << 5) + k];
        az += xv * We1[k * 128 + lane];
        at += xv * We1[k * 128 + 64 + lane];
    }
    float z = sigf(az), t = tanhf(at);
    float h = (1.f - z) * t;
    size_t o = (size_t)node * 128 + lane;
    c1[o] = (f16)fmaxf(h, 0.f);   // h1r half
    c1[o + 64] = (f16)h;          // h1 half
}

// ---------------- final: GRU combine + linear [64->2] ----------------
__global__ __launch_bounds__(256) void final_kernel(const f16* __restrict__ zb,
                                                    const f16* __restrict__ gT,  // stride 128
                                                    const f16* __restrict__ h2,  // stride 128
                                                    const float* __restrict__ lW, const float* __restrict__ lb,
                                                    float* __restrict__ out)
{
    int node = (blockIdx.x << 2) + (threadIdx.x >> 6);
    int lane = threadIdx.x & 63;
    float z = (float)zb[((size_t)node << 6) + lane];
    float d = z * (float)h2[(size_t)node * 128 + lane]
            + (1.f - z) * (float)gT[(size_t)node * 128 + lane];
    float s0 = d * lW[lane * 2];
    float s1 = d * lW[lane * 2 + 1];
    #pragma unroll
    for (int off = 32; off > 0; off >>= 1) {
        s0 += __shfl_down(s0, off);
        s1 += __shfl_down(s1, off);
    }
    if (lane == 0) {
        out[node * 2]     = s0 + lb[0];
        out[node * 2 + 1] = s1 + lb[1];
    }
}

// ---------------- driver ----------------

extern "C" void kernel_launch(void* const* d_in, const int* in_sizes, int n_in,
                              void* d_out, int out_size, void* d_ws, size_t ws_size,
                              hipStream_t stream)
{
    (void)in_sizes; (void)n_in; (void)out_size;
    const float* x   = (const float*)d_in[0];
    const int*  eidx = (const int*)d_in[1];
    const float* ew  = (const float*)d_in[2];
    const float* e1W = (const float*)d_in[3];
    const float* e1b = (const float*)d_in[4];
    const float* e2W = (const float*)d_in[5];
    const float* e2b = (const float*)d_in[6];
    const float* d1W = (const float*)d_in[7];
    const float* d1b = (const float*)d_in[8];
    const float* d2W = (const float*)d_in[9];
    const float* d2b = (const float*)d_in[10];
    const float* lW  = (const float*)d_in[11];
    const float* lb  = (const float*)d_in[12];
    const int* src = eidx;
    const int* dst = eidx + N_EDGES;
    const int N = N_NODES, E = N_EDGES;

    char* p = (char*)d_ws;
    auto carve = [&](size_t bytes) { char* r = p; p += (bytes + 255) & ~(size_t)255; return r; };
    size_t NC = (size_t)N * 128 * 2;             // [N,128] f16 = 25.6 MB
    int*   cntO  = (int*)carve((size_t)2 * N * 4);
    int*   cntI  = cntO + N;
    int*   rpO   = (int*)carve((size_t)(N + 1) * 4);
    int*   rpI   = (int*)carve((size_t)(N + 1) * 4);
    int*   slotO = (int*)carve((size_t)2 * E * 4);  // slotO|slotI; reused as adjO|adjI
    int*   slotI = slotO + E;
    int2*  adj2O = (int2*)carve((size_t)E * 8);     // {nbr, ew}; dead after finalize -> zb
    int2*  adj2I = (int2*)carve((size_t)E * 8);
    f16*   ct0   = (f16*)carve(NC);                 // t1o | (hi: gT in dec2)
    f16*   ct1   = (f16*)carve(NC);                 // s2o | (hi: g)
    f16*   ct2   = (f16*)carve(NC);                 // t1i
    f16*   ct3   = (f16*)carve(NC);                 // s2i
    float* do_inv = (float*)carve((size_t)N * 4);
    float* di_inv = (float*)carve((size_t)N * 4);
    f16*   xcat = (f16*)carve((size_t)N * 32 * 2);
    f16*   c1   = (f16*)carve(NC);   // h1r || h1
    f16*   c2   = (f16*)carve(NC);   // hA || h2
    f16* wE2   = (f16*)carve((size_t)10 * 128 * 32 * 2);
    f16* wD1zr = (f16*)carve((size_t)11 * 128 * 32 * 2);
    f16* wD1c  = (f16*)carve((size_t)11 * 64 * 32 * 2);
    f16* wD2zr = (f16*)carve((size_t)20 * 128 * 32 * 2);
    f16* wD2cA = (f16*)carve((size_t)10 * 64 * 32 * 2);
    f16* wD2cB = (f16*)carve((size_t)10 * 64 * 32 * 2);
    float* We1 = (float*)carve((size_t)1280 * 4);

    f16* zb = (f16*)adj2O;           // [N,64] — adj2 region dead after finalize
    f16* g1 = ct1 + 64;              // [N,64] stride 128 (cols 64-127 of ct1)
    f16* gT = ct0 + 64;              // [N,64] stride 128 (cols 64-127 of ct0)

    size_t needed = (size_t)(p - (char*)d_ws);
    if (needed > ws_size) return;   // clean failure (diagnosable) instead of fault

    const int eg = (E + 255) / 256;
    const int ng = (N + 255) / 256;
    const int GB = 25000;           // N/4 node-wave grid

    // --- graph prep ---
    hipMemsetAsync(cntO, 0, (size_t)2 * N * 4, stream);
    count_kernel<<<eg, 256, 0, stream>>>(src, dst, cntO, cntI, slotO, slotI);
    scan2_kernel<<<2, 1024, 0, stream>>>(cntO, rpO, cntI, rpI, N);
    fill_kernel<<<eg, 256, 0, stream>>>(src, dst, ew, rpO, rpI, slotO, slotI, adj2O, adj2I);
    int* adjO = slotO;   // slot arrays dead after fill; hold compact adjacency
    int* adjI = slotI;
    finalize_kernel<<<ng, 256, 0, stream>>>(rpO, adj2O, adjO, di_inv, rpI, adj2I, adjI, do_inv);

    // --- weight prep (single merged launch) ---
    prep_all<<<909, 256, 0, stream>>>(e1W, e2W, d1W, d2W,
                                      wE2, wD1zr, wD1c, wD2zr, wD2cA, wD2cB, We1);

    // --- x features + 2-channel Chebyshev basis (pure P hops, both dirs batched) ---
    xcat_init<<<(N * 32 + 255) / 256, 256, 0, stream>>>(x, xcat);
    dim3 ng2(ng, 2);
    prop2d_kernel<<<ng2, 256, 0, stream>>>(rpO, adjO, do_inv, 0, 2,
                                           rpI, adjI, di_inv, 0, 6, xcat);
    prop2d_kernel<<<ng2, 256, 0, stream>>>(rpO, adjO, do_inv, 2, 4,
                                           rpI, adjI, di_inv, 6, 8, xcat);

    auto props128 = [&](const f16* u) {   // ct0..ct3 = (t1o, s2o, t1i, s2i), full 128 cols
        dim3 pg(N / 16, 2);
        propk<16><<<pg, 256, 0, stream>>>(rpO, adjO, do_inv, u, ct0,
                                          rpI, adjI, di_inv, u, ct2, 128, 128);
        propk<16><<<pg, 256, 0, stream>>>(rpO, adjO, do_inv, ct0, ct1,
                                          rpI, adjI, di_inv, ct2, ct3, 128, 128);
    };
    auto props64 = [&](const f16* u, int ldu) {  // ct cols 0-63 only
        dim3 pg(N / 32, 2);
        propk<8><<<pg, 256, 0, stream>>>(rpO, adjO, do_inv, u, ct0,
                                         rpI, adjI, di_inv, u, ct2, ldu, 128);
        propk<8><<<pg, 256, 0, stream>>>(rpO, adjO, do_inv, ct0, ct1,
                                         rpI, adjI, di_inv, ct2, ct3, 128, 128);
    };
    const int gg = (N + 63) / 64;

    // enc1 -> c1 = relu(h1)||h1
    enc1_kernel<<<GB, 256, 0, stream>>>(xcat, We1, e1b, c1);
    // combined props of (h1r, h1)
    props128(c1);
    // enc2 (u = h1r half): fused GRU-h0 writes h2 into c2 cols 64-127
    mfma_gemm<10, 0, 128, 4><<<gg, 256, 0, stream>>>(
        c1, ct0, ct1, ct2, ct3, 128, 0, 128, 0, nullptr, wE2,
        nullptr, 0, e2b, e2b + 128, c2 + 64, 128, nullptr, 0, nullptr, 0, nullptr);
    // dec1 z|R (u = h1 half): z -> zb, g1 = R*h1 -> ct1 hi (row-private epilogue write)
    mfma_gemm<10, 1, 128, 5><<<gg, 256, 0, stream>>>(
        c1, ct0, ct1, ct2, ct3, 128, 64, 128, 64, xcat, wD1zr,
        nullptr, 0, d1b, d1b + 64, zb, 64, c1 + 64, 128, g1, 128, nullptr);
    // candidate props of g1 into ct cols 0-63 (g1 itself lives in ct1 cols 64-127)
    props64(g1, 128);
    // dec1 candidate: fused combine+relu writes hA into c2 cols 0-63
    mfma_gemm<10, 1, 64, 6><<<gg, 256, 0, stream>>>(
        g1, ct0, ct1, ct2, ct3, 128, 0, 128, 0, xcat, wD1c,
        nullptr, 0, d1b + 128, d1b + 128, c2, 128, c1 + 64, 128, nullptr, 0, zb);
    // combined props of (hA, h2)
    props128(c2);
    // dec2 z|R: single K=640 GEMM; z -> zb, g2 = R*h2 -> ct1 hi
    mfma_gemm<20, 0, 128, 5><<<gg, 256, 0, stream>>>(
        c2, ct0, ct1, ct2, ct3, 128, 0, 128, 0, nullptr, wD2zr,
        nullptr, 0, d2b, d2b + 64, zb, 64, c2 + 64, 128, g1, 128, nullptr);
    // dec2 candidate part A (hA rows) -> gT partial (ct0 hi; disjoint cols from readers)
    mfma_gemm<10, 0, 64, 0><<<gg, 256, 0, stream>>>(
        c2, ct0, ct1, ct2, ct3, 128, 0, 128, 0, nullptr, wD2cA,
        nullptr, 0, nullptr, nullptr, gT, 128, nullptr, 0, nullptr, 0, nullptr);
    // candidate props of g2 into ct cols 0-63
    props64(g1, 128);
    // dec2 candidate part B (g2 rows) + gT + bias + tanh -> gT (in-place add)
    mfma_gemm<10, 0, 64, 2><<<gg, 256, 0, stream>>>(
        g1, ct0, ct1, ct2, ct3, 128, 0, 128, 0, nullptr, wD2cB,
        gT, 128, d2b + 128, d2b + 128, gT, 128, nullptr, 0, nullptr, 0, nullptr);
    final_kernel<<<GB, 256, 0, stream>>>(zb, gT, c2 + 64, lW, lb, (float*)d_out);
}